// Round 5
// baseline (16.140 us; speedup 1.0000x reference)
//
#include <hip/hip_runtime.h>
#include <hip/hip_bf16.h>

// B=8, C=3, H=512, W=512, K=17. Output = per-pixel max over 16 segments of
// clip(lw+0.5 - dist(pixel,seg), 0, 1), broadcast to 3 channels.
// images' values are unused.
//
// Single kernel, 1024 blocks x 256 thr. Wave = one full 512-px row
// (8 px/lane). Mask phase: lane tests segment (lane&15)'s Y-range only
// (full-row tile makes the X test vacuous); __ballot -> wave-uniform 16-bit
// mask in SGPR; eval loop pulls segment params from the testing lane via
// v_readlane. No LDS, no extra dispatch.

constexpr int BB   = 8;
constexpr int CC   = 3;
constexpr int HH   = 512;
constexpr int WW   = 512;
constexpr int KPTS = 17;
constexpr int NSEG = KPTS - 1;   // 16

__device__ __forceinline__ float readlane_f(float v, int lane_sgpr) {
    return __int_as_float(__builtin_amdgcn_readlane(__float_as_int(v), lane_sgpr));
}

__global__ __launch_bounds__(256)
void stroke_kernel(const float* __restrict__ traj,   // [B,K,4] (t,x,y,z)
                   const int*   __restrict__ lw_p,   // scalar line_width
                   float*       __restrict__ out)    // [B,C,H,W]
{
    // 128 blocks/batch; block = 4 rows (4 waves); wave = 1 row, 8 px/lane.
    const int b    = blockIdx.x >> 7;
    const int tid  = threadIdx.x;
    const int wid  = tid >> 6;
    const int row  = ((blockIdx.x & 127) << 2) + wid;
    const int lane = tid & 63;
    const int xpx  = lane << 3;

    const float fy  = (float)row;
    const float fx0 = (float)xpx;
    const float lw  = (float)(*lw_p) + 0.5f;

    // ---- mask phase: lane tests segment (lane & 15), Y-range only ----
    const int s_l = lane & 15;
    const float* tp = traj + b * (KPTS * 4) + s_l * 4;
    const float x0 = tp[1], y0 = tp[2];
    const float x1 = tp[5], y1 = tp[6];
    const float dx = x1 - x0, dy = y1 - y0;
    const float rd = __builtin_amdgcn_rcpf(dx * dx + dy * dy + 1e-8f);

    const float ylo = fminf(y0, y1), yhi = fmaxf(y0, y1);
    const bool hit = !((ylo - fy >= lw) | (fy - yhi >= lw));
    unsigned int m = (unsigned int)__ballot(hit) & 0xFFFFu;
    m = __builtin_amdgcn_readfirstlane(m);

    // ---- eval phase: only Y-intersecting segments ----
    float acc[8];
    #pragma unroll
    for (int j = 0; j < 8; ++j) acc[j] = 0.0f;

    while (m) {
        const int s = __builtin_ctz(m);   // uniform -> s_ff1
        m &= m - 1;
        const float sx0 = readlane_f(x0, s);
        const float sy0 = readlane_f(y0, s);
        const float sdx = readlane_f(dx, s);
        const float sdy = readlane_f(dy, s);
        const float srd = readlane_f(rd, s);

        const float wy   = fy - sy0;
        const float wydy = wy * sdy;
        const float wxb  = fx0 - sx0;

        #pragma unroll
        for (int j = 0; j < 8; ++j) {
            const float wx = wxb + (float)j;
            float t = (wx * sdx + wydy) * srd;
            t = fminf(fmaxf(t, 0.0f), 1.0f);
            const float ddx  = wx - t * sdx;
            const float ddy  = wy - t * sdy;
            const float d2   = ddx * ddx + (ddy * ddy + 1e-12f);
            const float dist = __builtin_amdgcn_sqrtf(d2);
            const float cov  = fminf(lw - dist, 1.0f);   // low clamp via acc>=0
            acc[j] = fmaxf(acc[j], cov);
        }
    }

    const float4 v0 = make_float4(acc[0], acc[1], acc[2], acc[3]);
    const float4 v1 = make_float4(acc[4], acc[5], acc[6], acc[7]);
    const size_t plane = (size_t)HH * WW;
    float* p = out + (size_t)b * CC * plane + (size_t)row * WW + xpx;
    #pragma unroll
    for (int c = 0; c < CC; ++c) {
        *reinterpret_cast<float4*>(p + c * plane)     = v0;
        *reinterpret_cast<float4*>(p + c * plane + 4) = v1;
    }
}

extern "C" void kernel_launch(void* const* d_in, const int* in_sizes, int n_in,
                              void* d_out, int out_size, void* d_ws, size_t ws_size,
                              hipStream_t stream) {
    const float* traj = (const float*)d_in[1];   // trajectories [8,17,4]
    const int*   lw   = (const int*)d_in[2];     // line_width scalar
    float*       out  = (float*)d_out;           // [8,3,512,512] fp32

    stroke_kernel<<<BB * (HH / 4), 256, 0, stream>>>(traj, lw, out);
}

// Round 6
// 14.481 us; speedup vs baseline: 1.1145x; 1.1145x over previous
//
#include <hip/hip_runtime.h>
#include <hip/hip_bf16.h>

// B=8, C=3, H=512, W=512, K=17. Output = per-pixel max over 16 segments of
// clip(lw+0.5 - dist(pixel,seg), 0, 1), broadcast to 3 channels.
// images' values are unused.
//
// R4 structure (best measured: 14.2 us): single kernel, 2048 blocks x 256 thr.
// Wave = one row x 256px half-tile, 4 px/lane. Mask phase: lane tests segment
// (lane&15) bbox vs wave tile; __ballot -> uniform 16-bit mask in SGPR; eval
// loop pulls segment params from the testing lane via v_readlane.
// Micro-trims vs R4: early traj loads, explicit med3 clamp.

constexpr int BB   = 8;
constexpr int CC   = 3;
constexpr int HH   = 512;
constexpr int WW   = 512;
constexpr int KPTS = 17;
constexpr int NSEG = KPTS - 1;   // 16

__device__ __forceinline__ float readlane_f(float v, int lane_sgpr) {
    return __int_as_float(__builtin_amdgcn_readlane(__float_as_int(v), lane_sgpr));
}

__global__ __launch_bounds__(256)
void stroke_kernel(const float* __restrict__ traj,   // [B,K,4] (t,x,y,z)
                   const int*   __restrict__ lw_p,   // scalar line_width
                   float*       __restrict__ out)    // [B,C,H,W]
{
    const int b    = blockIdx.x >> 8;
    const int tid  = threadIdx.x;
    const int lane = tid & 63;

    // ---- issue segment loads first (hide VMEM latency under setup) ----
    const int s_l = lane & 15;
    const float* tp = traj + b * (KPTS * 4) + s_l * 4;
    const float x0 = tp[1], y0 = tp[2];
    const float x1 = tp[5], y1 = tp[6];

    const int wid  = tid >> 6;
    const int row  = ((blockIdx.x & 255) << 1) + (wid >> 1);
    const int half = wid & 1;
    const int xpx  = (half << 8) + (lane << 2);

    const float fy  = (float)row;
    const float fx0 = (float)xpx;
    const float lw  = (float)(*lw_p) + 0.5f;

    const float dx = x1 - x0, dy = y1 - y0;
    const float rd = __builtin_amdgcn_rcpf(dx * dx + dy * dy + 1e-8f);

    // ---- mask phase ----
    const float fxlo = (float)(half << 8);
    const float fxhi = fxlo + 255.0f;
    const float xlo = fminf(x0, x1), xhi = fmaxf(x0, x1);
    const float ylo = fminf(y0, y1), yhi = fmaxf(y0, y1);
    const bool hit = !((ylo - fy   >= lw) | (fy   - yhi >= lw) |
                       (xlo - fxhi >= lw) | (fxlo - xhi >= lw));
    unsigned int m = (unsigned int)__ballot(hit) & 0xFFFFu;
    m = __builtin_amdgcn_readfirstlane(m);

    // ---- eval phase: only intersecting segments ----
    float acc0 = 0.0f, acc1 = 0.0f, acc2 = 0.0f, acc3 = 0.0f;

    while (m) {
        const int s = __builtin_ctz(m);   // uniform -> s_ff1
        m &= m - 1;
        const float sx0 = readlane_f(x0, s);
        const float sy0 = readlane_f(y0, s);
        const float sdx = readlane_f(dx, s);
        const float sdy = readlane_f(dy, s);
        const float srd = readlane_f(rd, s);

        const float wy   = fy - sy0;
        const float wydy = wy * sdy;
        const float wxb  = fx0 - sx0;

        #pragma unroll
        for (int j = 0; j < 4; ++j) {
            const float wx = wxb + (float)j;
            float t = (wx * sdx + wydy) * srd;
            t = __builtin_amdgcn_fmed3f(t, 0.0f, 1.0f);
            const float ddx  = wx - t * sdx;
            const float ddy  = wy - t * sdy;
            const float d2   = ddx * ddx + (ddy * ddy + 1e-12f);
            const float dist = __builtin_amdgcn_sqrtf(d2);
            const float cov  = fminf(lw - dist, 1.0f);   // low clamp via acc>=0
            if (j == 0) acc0 = fmaxf(acc0, cov);
            if (j == 1) acc1 = fmaxf(acc1, cov);
            if (j == 2) acc2 = fmaxf(acc2, cov);
            if (j == 3) acc3 = fmaxf(acc3, cov);
        }
    }

    const float4 v = make_float4(acc0, acc1, acc2, acc3);
    const size_t plane = (size_t)HH * WW;
    float* p = out + (size_t)b * CC * plane + (size_t)row * WW + xpx;
    *reinterpret_cast<float4*>(p)             = v;
    *reinterpret_cast<float4*>(p + plane)     = v;
    *reinterpret_cast<float4*>(p + 2 * plane) = v;
}

extern "C" void kernel_launch(void* const* d_in, const int* in_sizes, int n_in,
                              void* d_out, int out_size, void* d_ws, size_t ws_size,
                              hipStream_t stream) {
    const float* traj = (const float*)d_in[1];   // trajectories [8,17,4]
    const int*   lw   = (const int*)d_in[2];     // line_width scalar
    float*       out  = (float*)d_out;           // [8,3,512,512] fp32

    stroke_kernel<<<BB * (HH / 2), 256, 0, stream>>>(traj, lw, out);
}